// Round 7
// baseline (295.701 us; speedup 1.0000x reference)
//
#include <hip/hip_runtime.h>

constexpr int N_ROWS = 131072;
constexpr int DIM    = 512;
constexpr int KP     = 512;
constexpr int BM     = 64;         // rows per block (4 waves x 16 rows)
constexpr int PC     = 32;         // panel cols
constexpr int NP     = KP / PC;    // 16 panels
constexpr int NKK    = DIM / 32;   // 16 MFMA k-steps (K=32 each)

typedef float    f32x4  __attribute__((ext_vector_type(4)));
typedef short    short8 __attribute__((ext_vector_type(8)));
typedef unsigned uintx4 __attribute__((ext_vector_type(4)));

__device__ inline unsigned short f2bf(float f) {
    unsigned u = __builtin_bit_cast(unsigned, f);
    unsigned r = (u + 0x7FFFu + ((u >> 16) & 1u)) >> 16;
    return (unsigned short)r;
}
__device__ inline unsigned pk2bf(float a, float b) {
    return (unsigned)f2bf(a) | ((unsigned)f2bf(b) << 16);
}
__device__ inline void gload_lds16(const unsigned short* g, unsigned short* l) {
    // LDS dest must be WAVE-UNIFORM; HW adds lane*16.
    __builtin_amdgcn_global_load_lds(
        (const __attribute__((address_space(1))) unsigned*)g,
        (__attribute__((address_space(3))) unsigned*)l, 16, 0, 0);
}

// ---------------------------------------------------------------------------
// prep: pn[c] = ||P[c]||^2; Pb = bf16(P) blocked [panel p=c/32][ku=k/8][col=c%32]
// as 16B units — exactly the linear order vq stages it into LDS.
// ---------------------------------------------------------------------------
__global__ void prep_kernel(const float* __restrict__ P, float* __restrict__ pn,
                            unsigned short* __restrict__ Pb) {
    const int c = blockIdx.x, l = threadIdx.x;   // l = k-unit 0..63
    const float* row = P + (size_t)c * DIM;
    float4 a = *reinterpret_cast<const float4*>(row + l * 8);
    float4 b = *reinterpret_cast<const float4*>(row + l * 8 + 4);
    float s = a.x*a.x + a.y*a.y + a.z*a.z + a.w*a.w
            + b.x*b.x + b.y*b.y + b.z*b.z + b.w*b.w;
    uintx4 pk = { pk2bf(a.x, a.y), pk2bf(a.z, a.w),
                  pk2bf(b.x, b.y), pk2bf(b.z, b.w) };
    const int p = c >> 5, cl = c & 31;
    const size_t unit = ((size_t)p * 64 + l) * 32 + cl;
    *reinterpret_cast<uintx4*>(Pb + unit * 8) = pk;
#pragma unroll
    for (int off = 32; off > 0; off >>= 1) s += __shfl_down(s, off);
    if (l == 0) pn[c] = s;
}

// ---------------------------------------------------------------------------
// vq: wave w owns rows w*16..w*16+15 with A (full K=512, bf16) in REGISTERS.
// 16 panels x 32 cols; per panel: stage 32KB B via global_load_lds, then
// 32 MFMA/wave; argmin folded in registers (wave-private rows, no merge).
// Loss: sum(best_dist) + sum(||x||^2)  ==  sum ||q-x||^2  (analytic).
// ---------------------------------------------------------------------------
__global__ __launch_bounds__(256, 4)
void vq_kernel(const float* __restrict__ X, const float* __restrict__ P,
               const unsigned short* __restrict__ Pb, const float* __restrict__ pn,
               float* __restrict__ out, double* __restrict__ lsum) {
    __shared__ __align__(16) unsigned short Bs[PC * DIM];   // 32 KB
    __shared__ int   idx_s[BM];
    __shared__ float ws[4];

    const int tid  = threadIdx.x;
    const int lane = tid & 63;
    const int wid  = tid >> 6;
    const int lr   = lane & 15;   // A row-in-wave / B col-in-panel
    const int lg   = lane >> 4;   // k-subgroup
    const size_t row0 = (size_t)blockIdx.x * BM;

    // ---- A load: X -> bf16 regs (A-frag layout), + ||x||^2 partial ----
    short8 a[NKK];
    float xsq = 0.f;
    const float* xb = X + (row0 + wid * 16 + lr) * DIM + lg * 8;
#pragma unroll
    for (int kk = 0; kk < NKK; ++kk) {
        float4 v0 = *reinterpret_cast<const float4*>(xb + kk * 32);
        float4 v1 = *reinterpret_cast<const float4*>(xb + kk * 32 + 4);
        xsq += v0.x*v0.x + v0.y*v0.y + v0.z*v0.z + v0.w*v0.w
             + v1.x*v1.x + v1.y*v1.y + v1.z*v1.z + v1.w*v1.w;
        uintx4 pk = { pk2bf(v0.x, v0.y), pk2bf(v0.z, v0.w),
                      pk2bf(v1.x, v1.y), pk2bf(v1.z, v1.w) };
        a[kk] = __builtin_bit_cast(short8, pk);
    }

    float bestv[4];
    int   besti[4];
#pragma unroll
    for (int j = 0; j < 4; ++j) { bestv[j] = 3.4e38f; besti[j] = 0; }

    // ---- panel loop ----
    for (int p = 0; p < NP; ++p) {
        if (p) __syncthreads();           // prior panel's MFMA done; Bs free
        // stage 32 KB: 2048 units, 8 per thread, lane-linear
        {
            const unsigned short* src =
                Pb + ((size_t)p * 2048 + wid * 64 + lane) * 8;
            unsigned short* dstu = Bs + (size_t)(wid * 64) * 8;  // wave-uniform
#pragma unroll
            for (int i = 0; i < 8; ++i)
                gload_lds16(src + (size_t)i * 256 * 8, dstu + (size_t)i * 256 * 8);
        }
        __syncthreads();                  // drain: Bs landed
        const float pn0 = pn[p * PC + lr];
        const float pn1 = pn[p * PC + 16 + lr];
        f32x4 acc0 = {0.f, 0.f, 0.f, 0.f}, acc1 = {0.f, 0.f, 0.f, 0.f};
#pragma unroll
        for (int kk = 0; kk < NKK; ++kk) {
            const int ku = kk * 4 + lg;
            short8 b0 = *reinterpret_cast<const short8*>(&Bs[(ku * 32 + lr) * 8]);
            short8 b1 = *reinterpret_cast<const short8*>(&Bs[(ku * 32 + 16 + lr) * 8]);
            acc0 = __builtin_amdgcn_mfma_f32_16x16x32_bf16(a[kk], b0, acc0, 0, 0, 0);
            acc1 = __builtin_amdgcn_mfma_f32_16x16x32_bf16(a[kk], b1, acc1, 0, 0, 0);
        }
        // fold panel into running best (ascending col order; strict <)
#pragma unroll
        for (int j = 0; j < 4; ++j) {
            float d0 = fmaf(-2.f, acc0[j], pn0);
            int   i0 = p * PC + lr;
            float d1 = fmaf(-2.f, acc1[j], pn1);
            if (d1 < d0) { d0 = d1; i0 = p * PC + 16 + lr; }
            if (d0 < bestv[j]) { bestv[j] = d0; besti[j] = i0; }
        }
    }

    // ---- wave-private argmin across the 16 cols-holding lanes ----
#pragma unroll
    for (int j = 0; j < 4; ++j) {
#pragma unroll
        for (int m = 1; m < 16; m <<= 1) {
            float ov = __shfl_xor(bestv[j], m);
            int   oi = __shfl_xor(besti[j], m);
            if (ov < bestv[j] || (ov == bestv[j] && oi < besti[j])) {
                bestv[j] = ov; besti[j] = oi;
            }
        }
        if (lr == 0) idx_s[wid * 16 + lg * 4 + j] = besti[j];
    }
    // loss partial: best dists (lr==0 lanes only) + ||x||^2 (all lanes)
    float lcl = xsq + (lr == 0 ? bestv[0] + bestv[1] + bestv[2] + bestv[3] : 0.f);
#pragma unroll
    for (int off = 32; off > 0; off >>= 1) lcl += __shfl_down(lcl, off);
    if (lane == 0) ws[wid] = lcl;
    __syncthreads();
    if (tid == 0)
        atomicAdd(lsum, (double)ws[0] + (double)ws[1]
                      + (double)ws[2] + (double)ws[3]);

    // ---- epilogue: out[r] = P[idx[r]] (P is L2-hot) ----
#pragma unroll 4
    for (int i = 0; i < 32; ++i) {
        int q = tid + i * 256;
        int r = q >> 7, f4 = q & 127;
        float4 pv = *reinterpret_cast<const float4*>(
            P + (size_t)idx_s[r] * DIM + f4 * 4);
        *reinterpret_cast<float4*>(out + (row0 + r) * DIM + f4 * 4) = pv;
    }
}

__global__ void finalize_kernel(const double* __restrict__ lsum,
                                float* __restrict__ out_loss) {
    out_loss[0] = (float)(1.25 * lsum[0] / ((double)N_ROWS * (double)DIM));
}

extern "C" void kernel_launch(void* const* d_in, const int* in_sizes, int n_in,
                              void* d_out, int out_size, void* d_ws, size_t ws_size,
                              hipStream_t stream) {
    const float* X = (const float*)d_in[0];
    const float* P = (const float*)d_in[1];
    float* out = (float*)d_out;

    // ws: [0,8) lsum; [256,+2K) pn; [4096,+512K) Pb
    double*         lsum = (double*)d_ws;
    float*          pn   = (float*)((char*)d_ws + 256);
    unsigned short* Pb   = (unsigned short*)((char*)d_ws + 4096);

    (void)hipMemsetAsync(d_ws, 0, 64, stream);
    prep_kernel<<<KP, 64, 0, stream>>>(P, pn, Pb);
    vq_kernel<<<N_ROWS / BM, 256, 0, stream>>>(X, P, Pb, pn, out, lsum);
    finalize_kernel<<<1, 1, 0, stream>>>(lsum, out + (size_t)N_ROWS * DIM);
    (void)hipMemcpyAsync(out + (size_t)N_ROWS * DIM + 1, P,
                         (size_t)KP * DIM * sizeof(float),
                         hipMemcpyDeviceToDevice, stream);
}

// Round 8
// 214.802 us; speedup vs baseline: 1.3766x; 1.3766x over previous
//
#include <hip/hip_runtime.h>

constexpr int N_ROWS = 131072;
constexpr int DIM    = 512;
constexpr int KP     = 512;
constexpr int BM     = 64;        // rows per block (4 waves x 16 rows)
constexpr int PC     = 32;        // panel cols
constexpr int NP     = KP / PC;   // 16 panels
// half-stage = 32 cols x 256 K = 1024 x 16B units = 16 KB, double-buffered

typedef float    f32x4  __attribute__((ext_vector_type(4)));
typedef short    short8 __attribute__((ext_vector_type(8)));
typedef unsigned uintx4 __attribute__((ext_vector_type(4)));

__device__ inline unsigned short f2bf(float f) {
    unsigned u = __builtin_bit_cast(unsigned, f);
    unsigned r = (u + 0x7FFFu + ((u >> 16) & 1u)) >> 16;
    return (unsigned short)r;
}
__device__ inline unsigned pk2bf(float a, float b) {
    return (unsigned)f2bf(a) | ((unsigned)f2bf(b) << 16);
}
__device__ inline void gload_lds16(const unsigned short* g, unsigned short* l) {
    // LDS dest must be WAVE-UNIFORM; HW adds lane*16.
    __builtin_amdgcn_global_load_lds(
        (const __attribute__((address_space(1))) unsigned*)g,
        (__attribute__((address_space(3))) unsigned*)l, 16, 0, 0);
}

// ---------------------------------------------------------------------------
// prep: pn[c] = ||P[c]||^2; Pb = bf16(P) blocked by half-stage:
// 16B unit (c, ku=k/8) -> [(p*2 + ku/32)*1024 + (ku%32)*32 + (c%32)], p=c/32.
// This is exactly the linear order vq stages into LDS.
// ---------------------------------------------------------------------------
__global__ void prep_kernel(const float* __restrict__ P, float* __restrict__ pn,
                            unsigned short* __restrict__ Pb) {
    const int c = blockIdx.x, l = threadIdx.x;   // l = k-unit 0..63
    const float* row = P + (size_t)c * DIM;
    float4 a = *reinterpret_cast<const float4*>(row + l * 8);
    float4 b = *reinterpret_cast<const float4*>(row + l * 8 + 4);
    float s = a.x*a.x + a.y*a.y + a.z*a.z + a.w*a.w
            + b.x*b.x + b.y*b.y + b.z*b.z + b.w*b.w;
    uintx4 pk = { pk2bf(a.x, a.y), pk2bf(a.z, a.w),
                  pk2bf(b.x, b.y), pk2bf(b.z, b.w) };
    const int p = c >> 5, cl = c & 31;
    const int h = l >> 5, kul = l & 31;
    const size_t unit = (size_t)(p * 2 + h) * 1024 + kul * 32 + cl;
    *reinterpret_cast<uintx4*>(Pb + unit * 8) = pk;
#pragma unroll
    for (int off = 32; off > 0; off >>= 1) s += __shfl_down(s, off);
    if (l == 0) pn[c] = s;
}

// ---------------------------------------------------------------------------
// vq: wave w owns rows w*16..+15, A (full K=512 bf16) in registers.
// 16 panels x 32 cols; each panel = 2 half-K stages (16 KB), double-buffered
// with counted vmcnt(4) so staging loads stay in flight across barriers.
// Argmin wave-private; loss analytic: sum(best) + sum(||x||^2).
// ---------------------------------------------------------------------------
__global__ __launch_bounds__(256, 3)
void vq_kernel(const float* __restrict__ X, const float* __restrict__ P,
               const unsigned short* __restrict__ Pb, const float* __restrict__ pn,
               float* __restrict__ out, double* __restrict__ lsum) {
    __shared__ __align__(16) unsigned short Bs[2][1024 * 8];  // 2 x 16 KB
    __shared__ float pn_s[KP];
    __shared__ int   idx_s[BM];
    __shared__ float wls[4];

    const int tid  = threadIdx.x;
    const int lane = tid & 63;
    const int wid  = tid >> 6;
    const int lr   = lane & 15;   // A row-in-wave / B col-in-panel
    const int lg   = lane >> 4;   // k-subgroup
    const size_t row0 = (size_t)blockIdx.x * BM;

    auto STAGE = [&](int hs, int bufp) {
        const unsigned short* src = Pb + ((size_t)hs * 1024 + wid * 64 + lane) * 8;
        unsigned short* dst = &Bs[bufp][(wid * 64) * 8];   // wave-uniform base
#pragma unroll
        for (int i = 0; i < 4; ++i)
            gload_lds16(src + i * 256 * 8, dst + i * 256 * 8);
    };

    STAGE(0, 0);   // prefetch panel0/half0; latency hides under A-load

    // pn -> LDS (keeps the counted-vmcnt loop free of stray global loads)
    pn_s[tid]       = pn[tid];
    pn_s[tid + 256] = pn[tid + 256];

    // ---- A: X -> bf16 registers (A-frag layout) + ||x||^2 partial ----
    short8 a[16];
    float xsq = 0.f;
    const float* xb = X + (row0 + wid * 16 + lr) * DIM + lg * 8;
#pragma unroll
    for (int kk = 0; kk < 16; ++kk) {
        float4 v0 = *reinterpret_cast<const float4*>(xb + kk * 32);
        float4 v1 = *reinterpret_cast<const float4*>(xb + kk * 32 + 4);
        xsq += v0.x*v0.x + v0.y*v0.y + v0.z*v0.z + v0.w*v0.w
             + v1.x*v1.x + v1.y*v1.y + v1.z*v1.z + v1.w*v1.w;
        uintx4 pk = { pk2bf(v0.x, v0.y), pk2bf(v0.z, v0.w),
                      pk2bf(v1.x, v1.y), pk2bf(v1.z, v1.w) };
        a[kk] = __builtin_bit_cast(short8, pk);
    }

    float bestv[4];
    int   besti[4];
#pragma unroll
    for (int j = 0; j < 4; ++j) { bestv[j] = 3.4e38f; besti[j] = 0; }

    f32x4 acc0 = {0.f, 0.f, 0.f, 0.f}, acc1 = {0.f, 0.f, 0.f, 0.f};

#define COMPUTE_HALF(H, BUF)                                                   \
    {                                                                          \
        __builtin_amdgcn_s_setprio(1);                                         \
        _Pragma("unroll")                                                      \
        for (int kkl = 0; kkl < 8; ++kkl) {                                    \
            const int kul = kkl * 4 + lg;                                      \
            short8 b0 = *reinterpret_cast<const short8*>(                      \
                &Bs[BUF][(kul * 32 + lr) * 8]);                                \
            short8 b1 = *reinterpret_cast<const short8*>(                      \
                &Bs[BUF][(kul * 32 + 16 + lr) * 8]);                           \
            acc0 = __builtin_amdgcn_mfma_f32_16x16x32_bf16(                    \
                a[(H) * 8 + kkl], b0, acc0, 0, 0, 0);                          \
            acc1 = __builtin_amdgcn_mfma_f32_16x16x32_bf16(                    \
                a[(H) * 8 + kkl], b1, acc1, 0, 0, 0);                          \
        }                                                                      \
        __builtin_amdgcn_s_setprio(0);                                         \
    }

    for (int p = 0; p < NP; ++p) {
        // ---- half 0: compute buf0 (stage 2p); prefetch 2p+1 -> buf1 ----
        __builtin_amdgcn_s_barrier();            // all waves consumed buf1
        STAGE(2 * p + 1, 1);
        asm volatile("s_waitcnt vmcnt(4)" ::: "memory");  // stage 2p landed
        __builtin_amdgcn_s_barrier();            // ... for every wave
        __builtin_amdgcn_sched_barrier(0);
        COMPUTE_HALF(0, 0)

        // ---- half 1: compute buf1 (stage 2p+1); prefetch 2p+2 -> buf0 ----
        __builtin_amdgcn_s_barrier();            // all waves consumed buf0
        if (p + 1 < NP) {
            STAGE(2 * p + 2, 0);
            asm volatile("s_waitcnt vmcnt(4)" ::: "memory");
        } else {
            asm volatile("s_waitcnt vmcnt(0)" ::: "memory");
        }
        __builtin_amdgcn_s_barrier();
        __builtin_amdgcn_sched_barrier(0);
        COMPUTE_HALF(1, 1)

        // ---- fold panel into running best (ascending index; strict <) ----
        const float pn0 = pn_s[p * PC + lr];
        const float pn1 = pn_s[p * PC + 16 + lr];
#pragma unroll
        for (int j = 0; j < 4; ++j) {
            float d0 = fmaf(-2.f, acc0[j], pn0);
            int   i0 = p * PC + lr;
            float d1 = fmaf(-2.f, acc1[j], pn1);
            if (d1 < d0) { d0 = d1; i0 = p * PC + 16 + lr; }
            if (d0 < bestv[j]) { bestv[j] = d0; besti[j] = i0; }
        }
        acc0 = {0.f, 0.f, 0.f, 0.f};
        acc1 = {0.f, 0.f, 0.f, 0.f};
    }
#undef COMPUTE_HALF

    // ---- wave-private argmin across the 16 col-holding lanes ----
#pragma unroll
    for (int j = 0; j < 4; ++j) {
#pragma unroll
        for (int m = 1; m < 16; m <<= 1) {
            float ov = __shfl_xor(bestv[j], m);
            int   oi = __shfl_xor(besti[j], m);
            if (ov < bestv[j] || (ov == bestv[j] && oi < besti[j])) {
                bestv[j] = ov; besti[j] = oi;
            }
        }
        if (lr == 0) idx_s[wid * 16 + lg * 4 + j] = besti[j];
    }
    // loss partial: best dists (lr==0 lanes) + ||x||^2 (all lanes)
    float lcl = xsq + (lr == 0 ? bestv[0] + bestv[1] + bestv[2] + bestv[3] : 0.f);
#pragma unroll
    for (int off = 32; off > 0; off >>= 1) lcl += __shfl_down(lcl, off);
    if (lane == 0) wls[wid] = lcl;
    __syncthreads();
    if (tid == 0)
        atomicAdd(lsum, (double)wls[0] + (double)wls[1]
                      + (double)wls[2] + (double)wls[3]);

    // ---- epilogue: out[r] = P[idx[r]] (P is L2-hot) ----
#pragma unroll 4
    for (int i = 0; i < 32; ++i) {
        int q = tid + i * 256;
        int r = q >> 7, f4 = q & 127;
        float4 pv = *reinterpret_cast<const float4*>(
            P + (size_t)idx_s[r] * DIM + f4 * 4);
        *reinterpret_cast<float4*>(out + (row0 + r) * DIM + f4 * 4) = pv;
    }
}

__global__ void finalize_kernel(const double* __restrict__ lsum,
                                float* __restrict__ out_loss) {
    out_loss[0] = (float)(1.25 * lsum[0] / ((double)N_ROWS * (double)DIM));
}

extern "C" void kernel_launch(void* const* d_in, const int* in_sizes, int n_in,
                              void* d_out, int out_size, void* d_ws, size_t ws_size,
                              hipStream_t stream) {
    const float* X = (const float*)d_in[0];
    const float* P = (const float*)d_in[1];
    float* out = (float*)d_out;

    // ws: [0,8) lsum; [256,+2K) pn; [4096,+512K) Pb
    double*         lsum = (double*)d_ws;
    float*          pn   = (float*)((char*)d_ws + 256);
    unsigned short* Pb   = (unsigned short*)((char*)d_ws + 4096);

    (void)hipMemsetAsync(d_ws, 0, 64, stream);
    prep_kernel<<<KP, 64, 0, stream>>>(P, pn, Pb);
    vq_kernel<<<N_ROWS / BM, 256, 0, stream>>>(X, P, Pb, pn, out, lsum);
    finalize_kernel<<<1, 1, 0, stream>>>(lsum, out + (size_t)N_ROWS * DIM);
    (void)hipMemcpyAsync(out + (size_t)N_ROWS * DIM + 1, P,
                         (size_t)KP * DIM * sizeof(float),
                         hipMemcpyDeviceToDevice, stream);
}